// Round 1
// baseline (685.287 us; speedup 1.0000x reference)
//
#include <hip/hip_runtime.h>
#include <math.h>

#define P_DIM 1024
#define R_DIM 128
#define M_DIM 128

// ---------------------------------------------------------------------------
// Phase 1: scores[i,j] = dot(rela[i,j,:], att_w) + att_b
// One 32-lane group per (i,j) pair. Lane l loads float4 at r = 4*l.
// ---------------------------------------------------------------------------
__global__ __launch_bounds__(256) void scores_kernel(
    const float* __restrict__ rela,
    const float* __restrict__ att_w,
    const float* __restrict__ att_b,
    float* __restrict__ scores)
{
    const int t    = blockIdx.x * 256 + threadIdx.x;
    const int pair = t >> 5;       // (i,j) flat index, 0..1048575
    const int lane = t & 31;

    const float4 w4 = reinterpret_cast<const float4*>(att_w)[lane];
    const float4 v  = reinterpret_cast<const float4*>(rela)[(size_t)pair * 32 + lane];

    float s = v.x * w4.x + v.y * w4.y + v.z * w4.z + v.w * w4.w;
    // butterfly within the 32-lane group (xor<=16 never crosses the 32 boundary)
    s += __shfl_xor(s, 16);
    s += __shfl_xor(s, 8);
    s += __shfl_xor(s, 4);
    s += __shfl_xor(s, 2);
    s += __shfl_xor(s, 1);

    if (lane == 0) scores[pair] = s + att_b[0];
}

// ---------------------------------------------------------------------------
// Phase 2: masked softmax over j (exact reference semantics: non-neighbors
// become -1e-6 and DO contribute to the denominator; weights are then zeroed),
// followed by out[i,:] = weights[i,:] @ hidden.
// 4 rows per block, 256 threads (one wave per row for the softmax).
// ---------------------------------------------------------------------------
__device__ __forceinline__ float fcomp(const float4& v, int k) {
    return k == 0 ? v.x : k == 1 ? v.y : k == 2 ? v.z : v.w;
}

__global__ __launch_bounds__(256) void attn_kernel(
    const float* __restrict__ scores,
    const int* __restrict__ nei,
    const float* __restrict__ hidden,
    float* __restrict__ out)
{
    __shared__ float  wsm[4][P_DIM];       // softmax weights, 16 KB
    __shared__ float4 part[4][8][32];      // matmul partials, 16 KB

    const int t    = threadIdx.x;
    const int wid  = t >> 6;               // wave id == row within block
    const int lane = t & 63;
    const int i0   = blockIdx.x << 2;
    const int i    = i0 + wid;

    // ---- per-wave softmax of row i (16 elements per lane) ----
    const float4* s4p = reinterpret_cast<const float4*>(scores + (size_t)i * P_DIM);
    const int4*   n4p = reinterpret_cast<const int4*>(nei + (size_t)i * P_DIM);

    float pv[16];
    unsigned mbits = 0;
    float lmax = -3.0e38f;
    #pragma unroll
    for (int c = 0; c < 4; ++c) {
        const int idx = c * 64 + lane;     // float4 index within row
        const float4 s4 = s4p[idx];
        const int4   n4 = n4p[idx];
        const float v0 = (n4.x > 0) ? s4.x : -1e-6f;
        const float v1 = (n4.y > 0) ? s4.y : -1e-6f;
        const float v2 = (n4.z > 0) ? s4.z : -1e-6f;
        const float v3 = (n4.w > 0) ? s4.w : -1e-6f;
        mbits |= ((n4.x > 0) ? 1u : 0u) << (c * 4 + 0);
        mbits |= ((n4.y > 0) ? 1u : 0u) << (c * 4 + 1);
        mbits |= ((n4.z > 0) ? 1u : 0u) << (c * 4 + 2);
        mbits |= ((n4.w > 0) ? 1u : 0u) << (c * 4 + 3);
        pv[c * 4 + 0] = v0; pv[c * 4 + 1] = v1;
        pv[c * 4 + 2] = v2; pv[c * 4 + 3] = v3;
        lmax = fmaxf(lmax, fmaxf(fmaxf(v0, v1), fmaxf(v2, v3)));
    }
    #pragma unroll
    for (int off = 32; off >= 1; off >>= 1)
        lmax = fmaxf(lmax, __shfl_xor(lmax, off));

    float lsum = 0.f;
    #pragma unroll
    for (int k = 0; k < 16; ++k) {
        const float e = __expf(pv[k] - lmax);
        pv[k] = e;
        lsum += e;
    }
    #pragma unroll
    for (int off = 32; off >= 1; off >>= 1)
        lsum += __shfl_xor(lsum, off);
    const float inv = 1.0f / lsum;

    #pragma unroll
    for (int c = 0; c < 4; ++c) {
        const int idx = c * 64 + lane;
        float4 o;
        o.x = ((mbits >> (c * 4 + 0)) & 1u) ? pv[c * 4 + 0] * inv : 0.f;
        o.y = ((mbits >> (c * 4 + 1)) & 1u) ? pv[c * 4 + 1] * inv : 0.f;
        o.z = ((mbits >> (c * 4 + 2)) & 1u) ? pv[c * 4 + 2] * inv : 0.f;
        o.w = ((mbits >> (c * 4 + 3)) & 1u) ? pv[c * 4 + 3] * inv : 0.f;
        reinterpret_cast<float4*>(wsm[wid])[idx] = o;
    }
    __syncthreads();

    // ---- matmul: thread owns float4-column c4, j-group h (128 j's) ----
    const int c4 = t & 31;
    const int h  = t >> 5;

    float4 acc[4];
    #pragma unroll
    for (int r = 0; r < 4; ++r) acc[r] = make_float4(0.f, 0.f, 0.f, 0.f);

    const int jbase = h * 128;
    #pragma unroll 2
    for (int jq = 0; jq < 32; ++jq) {
        const int j = jbase + jq * 4;
        float4 wq[4];
        #pragma unroll
        for (int r = 0; r < 4; ++r)
            wq[r] = *reinterpret_cast<const float4*>(&wsm[r][j]);  // LDS broadcast b128
        float4 hv[4];
        #pragma unroll
        for (int k = 0; k < 4; ++k)
            hv[k] = reinterpret_cast<const float4*>(hidden + (size_t)(j + k) * M_DIM)[c4];
        #pragma unroll
        for (int r = 0; r < 4; ++r) {
            #pragma unroll
            for (int k = 0; k < 4; ++k) {
                const float wc = fcomp(wq[r], k);
                acc[r].x += wc * hv[k].x;
                acc[r].y += wc * hv[k].y;
                acc[r].z += wc * hv[k].z;
                acc[r].w += wc * hv[k].w;
            }
        }
    }

    #pragma unroll
    for (int r = 0; r < 4; ++r) part[r][h][c4] = acc[r];
    __syncthreads();

    if (t < 128) {
        const int r = t >> 5;
        const int c = t & 31;
        float4 sum = part[r][0][c];
        #pragma unroll
        for (int hh = 1; hh < 8; ++hh) {
            const float4 p = part[r][hh][c];
            sum.x += p.x; sum.y += p.y; sum.z += p.z; sum.w += p.w;
        }
        reinterpret_cast<float4*>(out + (size_t)(i0 + r) * M_DIM)[c] = sum;
    }
}

// ---------------------------------------------------------------------------
extern "C" void kernel_launch(void* const* d_in, const int* in_sizes, int n_in,
                              void* d_out, int out_size, void* d_ws, size_t ws_size,
                              hipStream_t stream) {
    const float* hidden = (const float*)d_in[0];   // [1024,128]
    const float* rela   = (const float*)d_in[1];   // [1024,1024,128]
    // d_in[2] corr_index: unused by the reference
    const int*   nei    = (const int*)d_in[3];     // [1024,1024]
    const float* att_w  = (const float*)d_in[4];   // [128]
    const float* att_b  = (const float*)d_in[5];   // [1]
    float* out    = (float*)d_out;                 // [1024,128]
    float* scores = (float*)d_ws;                  // [1024*1024] fp32 = 4 MB scratch

    // 1M pairs, 8 pairs per 256-thread block
    scores_kernel<<<(P_DIM * P_DIM) / 8, 256, 0, stream>>>(rela, att_w, att_b, scores);
    attn_kernel<<<P_DIM / 4, 256, 0, stream>>>(scores, nei, hidden, out);
}